// Round 1
// baseline (2672.759 us; speedup 1.0000x reference)
//
#include <hip/hip_runtime.h>
#include <stdint.h>

#define N_ELEM 262144
#define NB 4096
#define TILE 32768
#define NBLK (N_ELEM / TILE) /* 8 */
#define GROUP 8

__device__ __forceinline__ unsigned key_of(float x) {
    unsigned u = __float_as_uint(x);
    return u ^ ((u & 0x80000000u) ? 0xFFFFFFFFu : 0x80000000u);
}

// Monotone (non-decreasing) float -> bucket map. Clamping never breaks
// correctness (in-bucket compare uses exact keys) — only load balance.
__device__ __forceinline__ int bucket_of(float x) {
    float f = (x + 8.0f) * 256.0f; // 4096 buckets over [-8, 8]
    int b = (int)floorf(f);
    b = b < 0 ? 0 : (b > NB - 1 ? NB - 1 : b);
    return b;
}

// --- Kernel A: per-(row,block) histogram of 4096 buckets -------------------
__global__ void hist_kernel(const float* __restrict__ x, int r0,
                            unsigned* __restrict__ blockHist) {
    __shared__ unsigned h[NB];
    const int crow = blockIdx.y, blk = blockIdx.x;
    for (int i = threadIdx.x; i < NB; i += 256) h[i] = 0;
    __syncthreads();
    const float4* p =
        (const float4*)(x + (size_t)(r0 + crow) * N_ELEM + (size_t)blk * TILE);
    for (int i = threadIdx.x; i < TILE / 4; i += 256) {
        float4 v = p[i];
        atomicAdd(&h[bucket_of(v.x)], 1u);
        atomicAdd(&h[bucket_of(v.y)], 1u);
        atomicAdd(&h[bucket_of(v.z)], 1u);
        atomicAdd(&h[bucket_of(v.w)], 1u);
    }
    __syncthreads();
    unsigned* out = blockHist + ((size_t)crow * NBLK + blk) * NB;
    for (int i = threadIdx.x; i < NB; i += 256) out[i] = h[i];
}

// --- Kernel B: per-row scan; converts blockHist counts -> scatter starts ---
// After this, blockHist[blk=0][b] is the row-level exclusive prefix (bucket base).
__global__ void scan_kernel(unsigned* __restrict__ blockHist) {
    __shared__ unsigned ssum[256];
    const int crow = blockIdx.x;
    unsigned* bh = blockHist + (size_t)crow * NBLK * NB;
    const int t = threadIdx.x;
    unsigned tot[16];
    unsigned threadSum = 0;
    for (int k = 0; k < 16; k++) {
        int b = t * 16 + k;
        unsigned s = 0;
        for (int blk = 0; blk < NBLK; blk++) s += bh[(size_t)blk * NB + b];
        tot[k] = s;
        threadSum += s;
    }
    ssum[t] = threadSum;
    __syncthreads();
    for (int off = 1; off < 256; off <<= 1) {
        unsigned v = (t >= off) ? ssum[t - off] : 0u;
        __syncthreads();
        ssum[t] += v;
        __syncthreads();
    }
    unsigned running = ssum[t] - threadSum; // exclusive thread base
    for (int k = 0; k < 16; k++) {
        int b = t * 16 + k;
        unsigned pre = running;
        for (int blk = 0; blk < NBLK; blk++) {
            size_t o = (size_t)blk * NB + b;
            unsigned c = bh[o];
            bh[o] = pre;
            pre += c;
        }
        running += tot[k];
    }
}

// --- Kernel C: scatter (key, origidx) records grouped by bucket ------------
__global__ void scatter_kernel(const float* __restrict__ x, int r0,
                               const unsigned* __restrict__ blockHist,
                               uint2* __restrict__ rec) {
    __shared__ unsigned cur[NB];
    const int crow = blockIdx.y, blk = blockIdx.x;
    const unsigned* bs = blockHist + ((size_t)crow * NBLK + blk) * NB;
    for (int i = threadIdx.x; i < NB; i += 256) cur[i] = bs[i];
    __syncthreads();
    const float4* p =
        (const float4*)(x + (size_t)(r0 + crow) * N_ELEM + (size_t)blk * TILE);
    uint2* rr = rec + (size_t)crow * N_ELEM;
    const int ib = blk * TILE;
    for (int i = threadIdx.x; i < TILE / 4; i += 256) {
        float4 v = p[i];
        int i0 = ib + i * 4;
        unsigned pos;
        pos = atomicAdd(&cur[bucket_of(v.x)], 1u);
        rr[pos] = make_uint2(key_of(v.x), (unsigned)(i0 + 0));
        pos = atomicAdd(&cur[bucket_of(v.y)], 1u);
        rr[pos] = make_uint2(key_of(v.y), (unsigned)(i0 + 1));
        pos = atomicAdd(&cur[bucket_of(v.z)], 1u);
        rr[pos] = make_uint2(key_of(v.z), (unsigned)(i0 + 2));
        pos = atomicAdd(&cur[bucket_of(v.w)], 1u);
        rr[pos] = make_uint2(key_of(v.w), (unsigned)(i0 + 3));
    }
}

// --- Kernel D: in-bucket exact ordinal rank via pairwise counting ----------
// side==0: write rank into rankP[origidx]
// side==1: gather rankP[origidx], accumulate sum(rp*rt) into S[row] (exact u64)
__global__ __launch_bounds__(64) void rank_kernel(
    const uint2* __restrict__ rec, const unsigned* __restrict__ blockHist,
    unsigned* __restrict__ rankP, unsigned long long* __restrict__ S, int r0,
    int trueSide) {
    const int b = blockIdx.x, crow = blockIdx.y;
    const unsigned* bs0 = blockHist + (size_t)crow * NBLK * NB; // blk 0 = row prefix
    unsigned base = bs0[b];
    unsigned end = (b + 1 < NB) ? bs0[b + 1] : (unsigned)N_ELEM;
    int n = (int)(end - base);
    if (n <= 0) return;
    const uint2* r = rec + (size_t)crow * N_ELEM + base;
    unsigned* rp = rankP + (size_t)crow * N_ELEM;
    __shared__ unsigned long long tk[64];
    const int t = threadIdx.x;
    unsigned long long acc = 0;

    for (int g0 = 0; g0 < n; g0 += 64 * GROUP) {
        unsigned long long myK[GROUP];
        unsigned myI[GROUP];
        int cnt[GROUP];
#pragma unroll
        for (int g = 0; g < GROUP; g++) {
            int j = g0 + t + 64 * g;
            myK[g] = ~0ull;
            myI[g] = 0;
            cnt[g] = 0;
            if (j < n) {
                uint2 e = r[j];
                myK[g] = ((unsigned long long)e.x << 32) | (unsigned)j;
                myI[g] = e.y;
            }
        }
        for (int tb = 0; tb < n; tb += 64) {
            int j = tb + t;
            unsigned long long K = ~0ull;
            if (j < n) {
                uint2 e = r[j];
                K = ((unsigned long long)e.x << 32) | (unsigned)j;
            }
            __syncthreads();
            tk[t] = K;
            __syncthreads();
            int lim = n - tb;
            if (lim > 64) lim = 64;
            for (int e = 0; e < lim; e++) {
                unsigned long long Kj = tk[e];
#pragma unroll
                for (int g = 0; g < GROUP; g++) cnt[g] += (Kj < myK[g]) ? 1 : 0;
            }
        }
#pragma unroll
        for (int g = 0; g < GROUP; g++) {
            int j = g0 + t + 64 * g;
            if (j < n) {
                unsigned rank = base + (unsigned)cnt[g] + 1u;
                if (!trueSide)
                    rp[myI[g]] = rank;
                else
                    acc += (unsigned long long)rp[myI[g]] * (unsigned long long)rank;
            }
        }
    }
    if (trueSide) {
        for (int off = 32; off > 0; off >>= 1) acc += __shfl_down(acc, off, 64);
        if (t == 0) atomicAdd(&S[r0 + crow], acc);
    }
}

// --- Kernel E: closed-form Pearson of two exact permutations + loss --------
__global__ void finalize_kernel(const unsigned long long* __restrict__ S, int B,
                                float* __restrict__ out) {
    __shared__ double sh[128];
    const int t = threadIdx.x;
    const double Nd = (double)N_ELEM;
    const double m = (Nd + 1.0) * 0.5;
    const double q = Nd * (Nd * Nd - 1.0) / 12.0; // sum of squared centered ranks
    double c = 0.0;
    if (t < B) {
        double num = (double)(long long)S[t] - Nd * m * m;
        c = num / sqrt(q * q + 1e-8);
    }
    sh[t] = c;
    __syncthreads();
    for (int off = 64; off > 0; off >>= 1) {
        if (t < off) sh[t] += sh[t + off];
        __syncthreads();
    }
    double mean = sh[0] / (double)B;
    __syncthreads();
    double d = (t < B) ? (c - mean) : 0.0;
    sh[t] = d * d;
    __syncthreads();
    for (int off = 64; off > 0; off >>= 1) {
        if (t < off) sh[t] += sh[t + off];
        __syncthreads();
    }
    if (t == 0) {
        double var = sh[0] / (double)B;
        double stdv = sqrt(var) + 1e-8;
        double icir = mean / stdv;
        out[0] = (float)(-icir + 0.1 * stdv);
    }
}

extern "C" void kernel_launch(void* const* d_in, const int* in_sizes, int n_in,
                              void* d_out, int out_size, void* d_ws,
                              size_t ws_size, hipStream_t stream) {
    const float* pred = (const float*)d_in[0];
    const float* tru = (const float*)d_in[1];
    const int B = in_sizes[0] / N_ELEM; // 90

    char* ws = (char*)d_ws;
    unsigned long long* S = (unsigned long long*)ws; // B * 8 bytes
    const size_t off0 = 4096;
    const size_t perRow =
        (size_t)NBLK * NB * 4 + (size_t)N_ELEM * 8 + (size_t)N_ELEM * 4;
    int R = (int)((ws_size > off0 ? ws_size - off0 : 0) / perRow);
    if (R > B) R = B;
    if (R < 1) R = 1;

    unsigned* blockHist = (unsigned*)(ws + off0);
    uint2* rec = (uint2*)(ws + off0 + (size_t)R * NBLK * NB * 4);
    unsigned* rankP =
        (unsigned*)(ws + off0 + (size_t)R * NBLK * NB * 4 + (size_t)R * N_ELEM * 8);

    hipMemsetAsync(S, 0, (size_t)B * 8, stream);

    for (int r0 = 0; r0 < B; r0 += R) {
        int RR = (B - r0 < R) ? (B - r0) : R;
        for (int side = 0; side < 2; side++) {
            const float* x = side ? tru : pred;
            hist_kernel<<<dim3(NBLK, RR), 256, 0, stream>>>(x, r0, blockHist);
            scan_kernel<<<RR, 256, 0, stream>>>(blockHist);
            scatter_kernel<<<dim3(NBLK, RR), 256, 0, stream>>>(x, r0, blockHist,
                                                               rec);
            rank_kernel<<<dim3(NB, RR), 64, 0, stream>>>(rec, blockHist, rankP, S,
                                                         r0, side);
        }
    }
    finalize_kernel<<<1, 128, 0, stream>>>(S, B, (float*)d_out);
}

// Round 2
// 2150.571 us; speedup vs baseline: 1.2428x; 1.2428x over previous
//
#include <hip/hip_runtime.h>
#include <stdint.h>

#define N_ELEM 262144
#define NB 4096
#define TILE 32768
#define NBLK (N_ELEM / TILE) /* 8 */
#define GROUP 8
#define CAP 1024 /* max in-bucket LDS records; normal data center bucket ~410 */

__device__ __forceinline__ unsigned key_of(float x) {
    unsigned u = __float_as_uint(x);
    return u ^ ((u & 0x80000000u) ? 0xFFFFFFFFu : 0x80000000u);
}

// 2^20 fine linear buckets over [-8,8]. floor((x+8)*65536) is monotone
// non-decreasing in x (add rounds monotonically, *65536 is exact).
// coarse = f20>>8 (4096), sub = f20&255. Clamping only affects load balance.
__device__ __forceinline__ int f20_of(float x) {
    int f = (int)floorf((x + 8.0f) * 65536.0f);
    f = f < 0 ? 0 : (f > (1 << 20) - 1 ? (1 << 20) - 1 : f);
    return f;
}

// --- Kernel A: per-(row,block) histogram of 4096 coarse buckets ------------
__global__ void hist_kernel(const float* __restrict__ x, int r0,
                            unsigned* __restrict__ blockHist) {
    __shared__ unsigned h[NB];
    const int crow = blockIdx.y, blk = blockIdx.x;
    for (int i = threadIdx.x; i < NB; i += 256) h[i] = 0;
    __syncthreads();
    const float4* p =
        (const float4*)(x + (size_t)(r0 + crow) * N_ELEM + (size_t)blk * TILE);
    for (int i = threadIdx.x; i < TILE / 4; i += 256) {
        float4 v = p[i];
        atomicAdd(&h[f20_of(v.x) >> 8], 1u);
        atomicAdd(&h[f20_of(v.y) >> 8], 1u);
        atomicAdd(&h[f20_of(v.z) >> 8], 1u);
        atomicAdd(&h[f20_of(v.w) >> 8], 1u);
    }
    __syncthreads();
    unsigned* out = blockHist + ((size_t)crow * NBLK + blk) * NB;
    for (int i = threadIdx.x; i < NB; i += 256) out[i] = h[i];
}

// --- Kernel B: per-row scan; converts blockHist counts -> scatter starts ---
__global__ void scan_kernel(unsigned* __restrict__ blockHist) {
    __shared__ unsigned ssum[256];
    const int crow = blockIdx.x;
    unsigned* bh = blockHist + (size_t)crow * NBLK * NB;
    const int t = threadIdx.x;
    unsigned tot[16];
    unsigned threadSum = 0;
    for (int k = 0; k < 16; k++) {
        int b = t * 16 + k;
        unsigned s = 0;
        for (int blk = 0; blk < NBLK; blk++) s += bh[(size_t)blk * NB + b];
        tot[k] = s;
        threadSum += s;
    }
    ssum[t] = threadSum;
    __syncthreads();
    for (int off = 1; off < 256; off <<= 1) {
        unsigned v = (t >= off) ? ssum[t - off] : 0u;
        __syncthreads();
        ssum[t] += v;
        __syncthreads();
    }
    unsigned running = ssum[t] - threadSum;
    for (int k = 0; k < 16; k++) {
        int b = t * 16 + k;
        unsigned pre = running;
        for (int blk = 0; blk < NBLK; blk++) {
            size_t o = (size_t)blk * NB + b;
            unsigned c = bh[o];
            bh[o] = pre;
            pre += c;
        }
        running += tot[k];
    }
}

// --- Kernel C: scatter (key, sub<<24|origidx) records grouped by bucket ----
__global__ void scatter_kernel(const float* __restrict__ x, int r0,
                               const unsigned* __restrict__ blockHist,
                               uint2* __restrict__ rec) {
    __shared__ unsigned cur[NB];
    const int crow = blockIdx.y, blk = blockIdx.x;
    const unsigned* bs = blockHist + ((size_t)crow * NBLK + blk) * NB;
    for (int i = threadIdx.x; i < NB; i += 256) cur[i] = bs[i];
    __syncthreads();
    const float4* p =
        (const float4*)(x + (size_t)(r0 + crow) * N_ELEM + (size_t)blk * TILE);
    uint2* rr = rec + (size_t)crow * N_ELEM;
    const int ib = blk * TILE;
    for (int i = threadIdx.x; i < TILE / 4; i += 256) {
        float4 v = p[i];
        int i0 = ib + i * 4;
        float vv[4] = {v.x, v.y, v.z, v.w};
#pragma unroll
        for (int k = 0; k < 4; k++) {
            int f = f20_of(vv[k]);
            unsigned pos = atomicAdd(&cur[f >> 8], 1u);
            rr[pos] = make_uint2(key_of(vv[k]),
                                 ((unsigned)(f & 255) << 24) | (unsigned)(i0 + k));
        }
    }
}

// --- Kernel D: in-bucket exact ordinal rank via 256-sub-bucket counting ----
// side==0: write rank into rankP[origidx]
// side==1: gather rankP[origidx], accumulate sum(rp*rt) into S[row] (exact u64)
__global__ __launch_bounds__(64) void rank_kernel(
    const uint2* __restrict__ rec, const unsigned* __restrict__ blockHist,
    unsigned* __restrict__ rankP, unsigned long long* __restrict__ S, int r0,
    int trueSide) {
    const int b = blockIdx.x, crow = blockIdx.y;
    const unsigned* bs0 = blockHist + (size_t)crow * NBLK * NB;
    unsigned base = bs0[b];
    unsigned end = (b + 1 < NB) ? bs0[b + 1] : (unsigned)N_ELEM;
    int n = (int)(end - base);
    if (n <= 0) return;
    const uint2* r = rec + (size_t)crow * N_ELEM + base;
    unsigned* rp = rankP + (size_t)crow * N_ELEM;
    const int t = threadIdx.x;
    unsigned long long acc = 0;

    if (n <= CAP) {
        __shared__ unsigned sk[CAP];        // exact keys
        __shared__ unsigned si[CAP];        // sub<<24 | origidx
        __shared__ unsigned short ord[CAP]; // slot ids grouped by sub-bucket
        __shared__ unsigned sh_cnt[256], sh_base[256], sh_cur[256];

        { // zero sub-hist
            int i4 = t * 4;
            sh_cnt[i4] = sh_cnt[i4 + 1] = sh_cnt[i4 + 2] = sh_cnt[i4 + 3] = 0;
        }
        __syncthreads();
        for (int j = t; j < n; j += 64) {
            uint2 e = r[j];
            sk[j] = e.x;
            si[j] = e.y;
            atomicAdd(&sh_cnt[e.y >> 24], 1u);
        }
        __syncthreads();
        { // exclusive prefix over 256 subs: 4 per lane + wave scan
            int i4 = t * 4;
            unsigned c0 = sh_cnt[i4], c1 = sh_cnt[i4 + 1], c2 = sh_cnt[i4 + 2],
                     c3 = sh_cnt[i4 + 3];
            unsigned s = c0 + c1 + c2 + c3;
            unsigned inc = s;
            for (int off = 1; off < 64; off <<= 1) {
                unsigned u = __shfl_up(inc, off, 64);
                if (t >= off) inc += u;
            }
            unsigned ex = inc - s;
            sh_base[i4] = ex;
            sh_cur[i4] = ex;
            ex += c0;
            sh_base[i4 + 1] = ex;
            sh_cur[i4 + 1] = ex;
            ex += c1;
            sh_base[i4 + 2] = ex;
            sh_cur[i4 + 2] = ex;
            ex += c2;
            sh_base[i4 + 3] = ex;
            sh_cur[i4 + 3] = ex;
        }
        __syncthreads();
        for (int j = t; j < n; j += 64) {
            unsigned pos = atomicAdd(&sh_cur[si[j] >> 24], 1u);
            ord[pos] = (unsigned short)j;
        }
        __syncthreads();
        for (int j = t; j < n; j += 64) {
            unsigned y = si[j];
            unsigned sub = y >> 24;
            unsigned start = sh_base[sub], cnt = sh_cnt[sub];
            unsigned long long myK = ((unsigned long long)sk[j] << 32) | (unsigned)j;
            unsigned c = 0;
            for (unsigned k = 0; k < cnt; k++) {
                unsigned jj = ord[start + k];
                unsigned long long K =
                    ((unsigned long long)sk[jj] << 32) | (unsigned)jj;
                c += (K < myK) ? 1u : 0u;
            }
            unsigned rank = base + start + c + 1u;
            unsigned idx = y & 0x00FFFFFFu;
            if (!trueSide)
                rp[idx] = rank;
            else
                acc += (unsigned long long)rp[idx] * (unsigned long long)rank;
        }
    } else { // fallback: chunked pairwise counting (never expected for N(0,1))
        __shared__ unsigned long long tk[64];
        for (int g0 = 0; g0 < n; g0 += 64 * GROUP) {
            unsigned long long myK[GROUP];
            unsigned myI[GROUP];
            int cnt[GROUP];
#pragma unroll
            for (int g = 0; g < GROUP; g++) {
                int j = g0 + t + 64 * g;
                myK[g] = ~0ull;
                myI[g] = 0;
                cnt[g] = 0;
                if (j < n) {
                    uint2 e = r[j];
                    myK[g] = ((unsigned long long)e.x << 32) | (unsigned)j;
                    myI[g] = e.y & 0x00FFFFFFu;
                }
            }
            for (int tb = 0; tb < n; tb += 64) {
                int j = tb + t;
                unsigned long long K = ~0ull;
                if (j < n) {
                    uint2 e = r[j];
                    K = ((unsigned long long)e.x << 32) | (unsigned)j;
                }
                __syncthreads();
                tk[t] = K;
                __syncthreads();
                int lim = n - tb;
                if (lim > 64) lim = 64;
                for (int e = 0; e < lim; e++) {
                    unsigned long long Kj = tk[e];
#pragma unroll
                    for (int g = 0; g < GROUP; g++) cnt[g] += (Kj < myK[g]) ? 1 : 0;
                }
            }
#pragma unroll
            for (int g = 0; g < GROUP; g++) {
                int j = g0 + t + 64 * g;
                if (j < n) {
                    unsigned rank = base + (unsigned)cnt[g] + 1u;
                    if (!trueSide)
                        rp[myI[g]] = rank;
                    else
                        acc += (unsigned long long)rp[myI[g]] *
                               (unsigned long long)rank;
                }
            }
        }
    }
    if (trueSide) {
        for (int off = 32; off > 0; off >>= 1) acc += __shfl_down(acc, off, 64);
        if (t == 0) atomicAdd(&S[r0 + crow], acc);
    }
}

// --- Kernel E: closed-form Pearson of two exact permutations + loss --------
__global__ void finalize_kernel(const unsigned long long* __restrict__ S, int B,
                                float* __restrict__ out) {
    __shared__ double sh[128];
    const int t = threadIdx.x;
    const double Nd = (double)N_ELEM;
    const double m = (Nd + 1.0) * 0.5;
    const double q = Nd * (Nd * Nd - 1.0) / 12.0;
    double c = 0.0;
    if (t < B) {
        double num = (double)(long long)S[t] - Nd * m * m;
        c = num / sqrt(q * q + 1e-8);
    }
    sh[t] = c;
    __syncthreads();
    for (int off = 64; off > 0; off >>= 1) {
        if (t < off) sh[t] += sh[t + off];
        __syncthreads();
    }
    double mean = sh[0] / (double)B;
    __syncthreads();
    double d = (t < B) ? (c - mean) : 0.0;
    sh[t] = d * d;
    __syncthreads();
    for (int off = 64; off > 0; off >>= 1) {
        if (t < off) sh[t] += sh[t + off];
        __syncthreads();
    }
    if (t == 0) {
        double var = sh[0] / (double)B;
        double stdv = sqrt(var) + 1e-8;
        double icir = mean / stdv;
        out[0] = (float)(-icir + 0.1 * stdv);
    }
}

extern "C" void kernel_launch(void* const* d_in, const int* in_sizes, int n_in,
                              void* d_out, int out_size, void* d_ws,
                              size_t ws_size, hipStream_t stream) {
    const float* pred = (const float*)d_in[0];
    const float* tru = (const float*)d_in[1];
    const int B = in_sizes[0] / N_ELEM; // 90

    char* ws = (char*)d_ws;
    unsigned long long* S = (unsigned long long*)ws;
    const size_t off0 = 4096;
    const size_t perRow =
        (size_t)NBLK * NB * 4 + (size_t)N_ELEM * 8 + (size_t)N_ELEM * 4;
    int R = (int)((ws_size > off0 ? ws_size - off0 : 0) / perRow);
    if (R > B) R = B;
    if (R < 1) R = 1;

    unsigned* blockHist = (unsigned*)(ws + off0);
    uint2* rec = (uint2*)(ws + off0 + (size_t)R * NBLK * NB * 4);
    unsigned* rankP =
        (unsigned*)(ws + off0 + (size_t)R * NBLK * NB * 4 + (size_t)R * N_ELEM * 8);

    hipMemsetAsync(S, 0, (size_t)B * 8, stream);

    for (int r0 = 0; r0 < B; r0 += R) {
        int RR = (B - r0 < R) ? (B - r0) : R;
        for (int side = 0; side < 2; side++) {
            const float* x = side ? tru : pred;
            hist_kernel<<<dim3(NBLK, RR), 256, 0, stream>>>(x, r0, blockHist);
            scan_kernel<<<RR, 256, 0, stream>>>(blockHist);
            scatter_kernel<<<dim3(NBLK, RR), 256, 0, stream>>>(x, r0, blockHist,
                                                               rec);
            rank_kernel<<<dim3(NB, RR), 64, 0, stream>>>(rec, blockHist, rankP, S,
                                                         r0, side);
        }
    }
    finalize_kernel<<<1, 128, 0, stream>>>(S, B, (float*)d_out);
}